// Round 7
// baseline (409.783 us; speedup 1.0000x reference)
//
#include <hip/hip_runtime.h>
#include <hip/hip_bf16.h>
#include <math.h>

// Problem constants (B=2, T=4096, D=2048, H=2048, W=4)
#define B_DIM 2
#define T_DIM 4096
#define D_DIM 2048
#define H_DIM 2048
#define W_K   4
#define M_DIM (B_DIM * T_DIM)   // 8192 tokens
#define N2_DIM (D_DIM * W_K)    // 8192

typedef __bf16 bf16x8 __attribute__((ext_vector_type(8)));
typedef float  f32x4  __attribute__((ext_vector_type(4)));

// m201-faithful: 256x256 tile, K-tile 64, double-buffered, 8 waves (2M x 4N),
// 4 phases/K-tile, half-tile stage schedule, vmcnt(6) once per K-tile.
#define BM 256
#define BN 256
#define BKT 64
#define XW_STRIDE 68   // f32 stride for epilogue x-window (2-way-free banks)

__device__ __forceinline__ unsigned short f2bf(float f) {
    unsigned int u = __float_as_uint(f);
    unsigned int r = (u + 0x7FFFu + ((u >> 16) & 1u)) >> 16;  // RNE
    return (unsigned short)r;
}

__device__ __forceinline__ float silu_f(float v) {
    return v / (1.0f + __expf(-v));
}

__global__ void cvt_f32_to_bf16(const float* __restrict__ in,
                                unsigned short* __restrict__ out, int n4) {
    int i = blockIdx.x * blockDim.x + threadIdx.x;
    if (i >= n4) return;
    float4 v = reinterpret_cast<const float4*>(in)[i];
    ushort4 o;
    o.x = f2bf(v.x); o.y = f2bf(v.y); o.z = f2bf(v.z); o.w = f2bf(v.w);
    reinterpret_cast<ushort4*>(out)[i] = o;
}

// LDS tile: [256 rows][64 bf16] = 128 B/row, XOR swizzle:
//   phys = r*128 + (kb ^ ((r&7)<<4))
// ds_read_b128: 16 lanes share kb with rows r..r+15 -> (r&7) spreads them over
// all 8 16B slots (32 banks); rows repeat once = exact 2-way aliasing (free).
__device__ __forceinline__ bf16x8 lds_frag(const unsigned short* buf, int r, int kb) {
    int lin = r * 128 + (kb ^ ((r & 7) << 4));
    return *reinterpret_cast<const bf16x8*>(reinterpret_cast<const char*>(buf) + lin);
}

#define BARRIER()    __builtin_amdgcn_s_barrier()
#define WAIT_LGKM0() asm volatile("s_waitcnt lgkmcnt(0)" ::: "memory")
#define WAIT_VM(N)   asm volatile("s_waitcnt vmcnt(" #N ")" ::: "memory")

// Stage one 8KB chunk (64 rows x 64 cols bf16) of a K-tile into LDS.
// global_load_lds dest = wave-uniform base + lane*16; swizzle applied by
// inverse-permuting the per-lane GLOBAL source (rule #21, XOR involution).
// Lane l covers row chunk*64 + wave*8 + (l>>3), slot ((l&7)^((l>>3)&7)).
#define STAGE64(basePtr, ko, dstUshort, chunk) \
    __builtin_amdgcn_global_load_lds( \
        (const __attribute__((address_space(1))) void*)((basePtr) + soff + (size_t)(chunk) * 64 * K + (ko)), \
        (__attribute__((address_space(3))) void*)(reinterpret_cast<char*>(dstUshort) + ((chunk) << 13) + (wave << 10)), \
        16, 0, 0)

// 16 MFMA of one phase: M-group mg (2 Mfrags) x 4 Nfrags x 2 K-steps.
#define PH_MFMA(mg) \
    _Pragma("unroll") for (int kk = 0; kk < 2; ++kk) \
    _Pragma("unroll") for (int mrel = 0; mrel < 2; ++mrel) \
    _Pragma("unroll") for (int nf = 0; nf < 4; ++nf) \
        acc[(mg)*2 + mrel][nf] = __builtin_amdgcn_mfma_f32_16x16x32_bf16( \
            afrag[mrel][kk], bfrag[nf][kk], acc[(mg)*2 + mrel][nf], 0, 0, 0)

// One K-tile = 4 phases (m201 schedule). Stage units (clobber-safe):
//   ph1: A2(j+1) -> other buf chunks 1,3 (A mg2,3 of j-1 consumed at j-1 ph3/4)
//   ph2: B1(j+2) -> this buf chunks 0,1  (B fully read at ph1)
//   ph3: A1(j+2) -> this buf chunks 0,2  (A mg0,1 read at ph1,ph2)
//   ph4: B2(j+2) -> this buf chunks 2,3; vmcnt(6) = 3 half-tiles stay in flight
// Steady state at ph4 pre-wait: 14 loads out; vmcnt(6) retires exactly
// B1,A1,B2(j+1) + A2(j+1) -> tile j+1 ready; B1,A1,B2(j+2) remain.
#define KTILE_M(bi, jj, S1, S2, S3, S4, VMN) do { \
    const unsigned short* tA = smem + (bi) * 16384; \
    const unsigned short* tB = smem + 32768 + (bi) * 16384; \
    unsigned short* oA = smem + ((bi) ^ 1) * 16384; \
    unsigned short* cA = smem + (bi) * 16384; \
    unsigned short* cB = smem + 32768 + (bi) * 16384; \
    /* ph1: read all B (8) + A mg0 (4) = 12 ds_read_b128; stage A2(j+1) */ \
    _Pragma("unroll") for (int nf = 0; nf < 4; ++nf) \
    _Pragma("unroll") for (int kk = 0; kk < 2; ++kk) \
        bfrag[nf][kk] = lds_frag(tB, wc*64 + nf*16 + ln15, kk*64 + kb16); \
    _Pragma("unroll") for (int mrel = 0; mrel < 2; ++mrel) \
    _Pragma("unroll") for (int kk = 0; kk < 2; ++kk) \
        afrag[mrel][kk] = lds_frag(tA, wr*128 + mrel*16 + ln15, kk*64 + kb16); \
    if (S1) { const int ko = ((jj) + 1) << 6; \
        STAGE64(baseA, ko, oA, 1); STAGE64(baseA, ko, oA, 3); } \
    BARRIER(); WAIT_LGKM0(); \
    __builtin_amdgcn_s_setprio(1); PH_MFMA(0); __builtin_amdgcn_s_setprio(0); \
    BARRIER(); \
    /* ph2: A mg1; stage B1(j+2) */ \
    _Pragma("unroll") for (int mrel = 0; mrel < 2; ++mrel) \
    _Pragma("unroll") for (int kk = 0; kk < 2; ++kk) \
        afrag[mrel][kk] = lds_frag(tA, wr*128 + 32 + mrel*16 + ln15, kk*64 + kb16); \
    if (S2) { const int ko = ((jj) + 2) << 6; \
        STAGE64(baseB, ko, cB, 0); STAGE64(baseB, ko, cB, 1); } \
    BARRIER(); WAIT_LGKM0(); \
    __builtin_amdgcn_s_setprio(1); PH_MFMA(1); __builtin_amdgcn_s_setprio(0); \
    BARRIER(); \
    /* ph3: A mg2; stage A1(j+2) */ \
    _Pragma("unroll") for (int mrel = 0; mrel < 2; ++mrel) \
    _Pragma("unroll") for (int kk = 0; kk < 2; ++kk) \
        afrag[mrel][kk] = lds_frag(tA, wr*128 + 64 + mrel*16 + ln15, kk*64 + kb16); \
    if (S3) { const int ko = ((jj) + 2) << 6; \
        STAGE64(baseA, ko, cA, 0); STAGE64(baseA, ko, cA, 2); } \
    BARRIER(); WAIT_LGKM0(); \
    __builtin_amdgcn_s_setprio(1); PH_MFMA(2); __builtin_amdgcn_s_setprio(0); \
    BARRIER(); \
    /* ph4: A mg3; stage B2(j+2); counted vmcnt (never drains in main loop) */ \
    _Pragma("unroll") for (int mrel = 0; mrel < 2; ++mrel) \
    _Pragma("unroll") for (int kk = 0; kk < 2; ++kk) \
        afrag[mrel][kk] = lds_frag(tA, wr*128 + 96 + mrel*16 + ln15, kk*64 + kb16); \
    if (S4) { const int ko = ((jj) + 2) << 6; \
        STAGE64(baseB, ko, cB, 2); STAGE64(baseB, ko, cB, 3); } \
    WAIT_VM(VMN); \
    BARRIER(); WAIT_LGKM0(); \
    __builtin_amdgcn_s_setprio(1); PH_MFMA(3); __builtin_amdgcn_s_setprio(0); \
    BARRIER(); \
} while (0)

// NT GEMM, 256^2 dbuf 4-phase/K64: C = A[M,K] * Bm[N,K]^T, bf16 in, fp32 acc.
// EPI=0: Hout = bf16(silu(C)); EPI=1: fused bias + dynamic causal conv + silu
// with LDS-staged x-window.
template <int EPI>
__global__ __launch_bounds__(512, 2)
void gemm8p(const unsigned short* __restrict__ A,
            const unsigned short* __restrict__ Bm,
            int M, int N, int K,
            unsigned short* __restrict__ Hout,
            const float* __restrict__ bias,
            const float* __restrict__ Xf,
            float* __restrict__ Out) {
    __shared__ __align__(16) unsigned short smem[65536];  // 128 KB

    const int tid  = threadIdx.x;
    const int wave = tid >> 6, lane = tid & 63;
    const int wr = wave >> 2, wc = wave & 3;        // 2M x 4N wave grid
    const int ln15 = lane & 15;
    const int kb16 = (lane >> 4) * 16;              // 16B k-slot within 128B row

    // Column-band XCD map (bijective; needs GX % 8 == 0):
    // XCD = bid&7 owns GX/8 consecutive block-columns, traversed COLUMN-major.
    // The 32 concurrently-resident blocks of an XCD = one full block-column:
    // concurrent B footprint = 1 B-panel (1MB, L2-resident); A-panels are the
    // same row-set across all XCDs (L3-shared, reused across rounds).
    const int GX = gridDim.x, GY = gridDim.y;
    const int bid = blockIdx.y * GX + blockIdx.x;
    const int xcd = bid & 7;
    const int idx = bid >> 3;                 // 0 .. GX*GY/8 - 1
    const int cpx = GX >> 3;                  // cols per XCD
    const int c   = idx / GY;                 // col within band (col-major)
    const int r   = idx - c * GY;             // row
    const int bx  = xcd * cpx + c;
    const int by  = r;
    const int m0 = by * BM, n0 = bx * BN;

    const int nk = K >> 6;   // K-tiles of 64 (=32 here)

    // Per-thread staging offset: lane l -> row wave*8 + (l>>3),
    // slot ((l&7)^((l>>3)&7)) (inverse swizzle; row&7 == (l>>3)&7).
    const int srow = (wave << 3) + (lane >> 3);
    const int scol = (((lane & 7) ^ ((lane >> 3) & 7)) << 3);  // ushort units
    const size_t soff = (size_t)srow * K + scol;
    const unsigned short* baseA = A + (size_t)m0 * K;
    const unsigned short* baseB = Bm + (size_t)n0 * K;

    f32x4 acc[8][4];
#pragma unroll
    for (int i = 0; i < 8; ++i)
#pragma unroll
        for (int j = 0; j < 4; ++j) acc[i][j] = (f32x4)0.0f;

    bf16x8 bfrag[4][2], afrag[2][2];

    // ---- prologue: tile 0 all 4 halves + tile 1's B1,A1,B2 (A2(1) at ph1) ----
    {
        unsigned short* dA0 = smem;
        unsigned short* dB0 = smem + 32768;
        unsigned short* dA1 = smem + 16384;
        unsigned short* dB1 = smem + 49152;
        STAGE64(baseB, 0, dB0, 0); STAGE64(baseB, 0, dB0, 1);
        STAGE64(baseB, 0, dB0, 2); STAGE64(baseB, 0, dB0, 3);
        STAGE64(baseA, 0, dA0, 0); STAGE64(baseA, 0, dA0, 1);
        STAGE64(baseA, 0, dA0, 2); STAGE64(baseA, 0, dA0, 3);
        STAGE64(baseB, BKT, dB1, 0); STAGE64(baseB, BKT, dB1, 1);  // B1(1)
        STAGE64(baseA, BKT, dA1, 0); STAGE64(baseA, BKT, dA1, 2);  // A1(1)
        STAGE64(baseB, BKT, dB1, 2); STAGE64(baseB, BKT, dB1, 3);  // B2(1)
    }
    WAIT_VM(6);   // tile 0 landed; tile 1's 3 halves in flight
    BARRIER();

    // ---- main loop: 2 K-tiles per iteration; last two tiles peeled ----
    for (int it = 0; it < (nk >> 1) - 1; ++it) {
        const int j = it << 1;
        KTILE_M(0, j,     1, 1, 1, 1, 6);
        KTILE_M(1, j + 1, 1, 1, 1, 1, 6);
    }
    KTILE_M(0, nk - 2, 1, 0, 0, 0, 0);   // stage only A2(nk-1); drain
    KTILE_M(1, nk - 1, 0, 0, 0, 0, 0);
    BARRIER();

    // ---- epilogue ----
    if (EPI == 0) {
#pragma unroll
        for (int mf = 0; mf < 8; ++mf) {
            int rowb = m0 + wr * 128 + mf * 16 + (lane >> 4) * 4;
#pragma unroll
            for (int nf = 0; nf < 4; ++nf) {
                int col = n0 + wc * 64 + nf * 16 + ln15;
#pragma unroll
                for (int r2 = 0; r2 < 4; ++r2) {
                    Hout[(size_t)(rowb + r2) * N + col] = f2bf(silu_f(acc[mf][nf][r2]));
                }
            }
        }
    } else {
        // Stage x-window into LDS: rows ts = t0-3 .. t0+255 (259), 64 d cols.
        const int t0 = m0 & (T_DIM - 1);
        const int bidx = m0 >> 12;
        const int dbase = n0 >> 2;
        float* Xw = reinterpret_cast<float*>(smem);   // [259][XW_STRIDE]
        for (int idx2 = tid; idx2 < 259 * 16; idx2 += 512) {
            int rw = idx2 >> 4, q = (idx2 & 15) << 2;
            int ts = t0 - 3 + rw;
            float4 v = make_float4(0.f, 0.f, 0.f, 0.f);
            if (ts >= 0)
                v = *reinterpret_cast<const float4*>(
                    &Xf[((size_t)bidx * T_DIM + ts) * D_DIM + dbase + q]);
            float* p = &Xw[rw * XW_STRIDE + q];
            p[0] = v.x; p[1] = v.y; p[2] = v.z; p[3] = v.w;
        }
        __syncthreads();

        // k = C + bias; out[b,t,d] = silu(sum_w x[b,t-3+w,d] * k[t, d*4+w])
        // col -> (d = col>>2, w = col&3); 4-lane butterfly sums over w.
        const int dl = wc * 16 + (ln15 >> 2);   // + nf*4 below
        const int w = lane & 3;
#pragma unroll
        for (int mf = 0; mf < 8; ++mf) {
            int lrow0 = wr * 128 + mf * 16 + (lane >> 4) * 4;
#pragma unroll
            for (int nf = 0; nf < 4; ++nf) {
                int col = n0 + wc * 64 + nf * 16 + ln15;
                int d = col >> 2;
                float bv = bias[col];
#pragma unroll
                for (int r2 = 0; r2 < 4; ++r2) {
                    int lrow = lrow0 + r2;
                    float v = acc[mf][nf][r2] + bv;
                    float xv = Xw[(lrow + w) * XW_STRIDE + dl + nf * 4];
                    float p = v * xv;
                    p += __shfl_xor(p, 1);
                    p += __shfl_xor(p, 2);
                    if ((lane & 3) == 0) {
                        Out[((size_t)bidx * T_DIM + (t0 + lrow)) * D_DIM + d] = silu_f(p);
                    }
                }
            }
        }
    }
}

extern "C" void kernel_launch(void* const* d_in, const int* in_sizes, int n_in,
                              void* d_out, int out_size, void* d_ws, size_t ws_size,
                              hipStream_t stream) {
    const float* x    = (const float*)d_in[0];  // [B,T,D]
    const float* w1   = (const float*)d_in[1];  // [H,D]
    const float* w2w  = (const float*)d_in[2];  // [D*W,H]
    const float* w2b  = (const float*)d_in[3];  // [D*W]
    float* out = (float*)d_out;

    // Workspace: ws0 = xb [M,D] bf16 (later reused for w2wb [N2,H] bf16),
    //            ws1 = w1b [H,D] bf16, ws2 = hb [M,H] bf16.
    unsigned short* ws0 = (unsigned short*)d_ws;
    unsigned short* ws1 = ws0 + (size_t)M_DIM * D_DIM;
    unsigned short* ws2 = ws1 + (size_t)H_DIM * D_DIM;

    const int CT = 256;
    {
        int n4 = (M_DIM * D_DIM) / 4;
        cvt_f32_to_bf16<<<(n4 + CT - 1) / CT, CT, 0, stream>>>(x, ws0, n4);
    }
    {
        int n4 = (H_DIM * D_DIM) / 4;
        cvt_f32_to_bf16<<<(n4 + CT - 1) / CT, CT, 0, stream>>>(w1, ws1, n4);
    }
    // GEMM1: hb = silu(xb @ w1b^T)  [8192, 2048]
    gemm8p<0><<<dim3(H_DIM / BN, M_DIM / BM), 512, 0, stream>>>(
        ws0, ws1, M_DIM, H_DIM, D_DIM, ws2, nullptr, nullptr, nullptr);
    // convert w2_w into ws0 (xb now dead)
    {
        int n4 = (N2_DIM * H_DIM) / 4;
        cvt_f32_to_bf16<<<(n4 + CT - 1) / CT, CT, 0, stream>>>(w2w, ws0, n4);
    }
    // GEMM2 + fused bias/conv/silu -> out
    gemm8p<1><<<dim3(N2_DIM / BN, M_DIM / BM), 512, 0, stream>>>(
        ws2, ws0, M_DIM, N2_DIM, H_DIM, nullptr, w2b, x, out);
}

// Round 8
// 401.798 us; speedup vs baseline: 1.0199x; 1.0199x over previous
//
#include <hip/hip_runtime.h>
#include <hip/hip_bf16.h>
#include <math.h>

// Problem constants (B=2, T=4096, D=2048, H=2048, W=4)
#define B_DIM 2
#define T_DIM 4096
#define D_DIM 2048
#define H_DIM 2048
#define W_K   4
#define M_DIM (B_DIM * T_DIM)   // 8192 tokens
#define N2_DIM (D_DIM * W_K)    // 8192

typedef __bf16 bf16x8 __attribute__((ext_vector_type(8)));
typedef float  f32x4  __attribute__((ext_vector_type(4)));

// 256x256 tile, K-tile 64, double-buffered, 8 waves (2M x 4N).
// 2 barriers per K-tile; compiler-scheduled ds_read/MFMA overlap within
// each barrier-free region (counted lgkmcnt auto-inserted by hipcc).
#define BM 256
#define BN 256
#define BKT 64
#define XW_STRIDE 68   // f32 stride for epilogue x-window (2-way-free banks)

__device__ __forceinline__ unsigned short f2bf(float f) {
    unsigned int u = __float_as_uint(f);
    unsigned int r = (u + 0x7FFFu + ((u >> 16) & 1u)) >> 16;  // RNE
    return (unsigned short)r;
}

__device__ __forceinline__ float silu_f(float v) {
    return v / (1.0f + __expf(-v));
}

__global__ void cvt_f32_to_bf16(const float* __restrict__ in,
                                unsigned short* __restrict__ out, int n4) {
    int i = blockIdx.x * blockDim.x + threadIdx.x;
    if (i >= n4) return;
    float4 v = reinterpret_cast<const float4*>(in)[i];
    ushort4 o;
    o.x = f2bf(v.x); o.y = f2bf(v.y); o.z = f2bf(v.z); o.w = f2bf(v.w);
    reinterpret_cast<ushort4*>(out)[i] = o;
}

// LDS tile: [256 rows][64 bf16] = 128 B/row, XOR swizzle:
//   phys = r*128 + (kb ^ ((r&7)<<4))  -> exact 2-way bank aliasing (free).
__device__ __forceinline__ bf16x8 lds_frag(const unsigned short* buf, int r, int kb) {
    int lin = r * 128 + (kb ^ ((r & 7) << 4));
    return *reinterpret_cast<const bf16x8*>(reinterpret_cast<const char*>(buf) + lin);
}

#define BARRIER()    __builtin_amdgcn_s_barrier()
#define WAIT_VM(N)   asm volatile("s_waitcnt vmcnt(" #N ")" ::: "memory")

// Stage one 8KB chunk (64 rows x 64 cols bf16) of a K-tile into LDS.
// Dest = wave-uniform base + lane*16 (linear); swizzle applied by inverse-
// permuting the per-lane GLOBAL source (rule #21, XOR involution).
#define STAGE64(basePtr, ko, dstUshort, chunk) \
    __builtin_amdgcn_global_load_lds( \
        (const __attribute__((address_space(1))) void*)((basePtr) + soff + (size_t)(chunk) * 64 * K + (ko)), \
        (__attribute__((address_space(3))) void*)(reinterpret_cast<char*>(dstUshort) + ((chunk) << 13) + (wave << 10)), \
        16, 0, 0)

// 16 MFMA for one M-group: 2 Mfrags x 4 Nfrags x 2 K-steps.
#define MG_MFMA(mg, AF) \
    _Pragma("unroll") for (int kk = 0; kk < 2; ++kk) \
    _Pragma("unroll") for (int mrel = 0; mrel < 2; ++mrel) \
    _Pragma("unroll") for (int nf = 0; nf < 4; ++nf) \
        acc[(mg)*2 + mrel][nf] = __builtin_amdgcn_mfma_f32_16x16x32_bf16( \
            AF[mrel][kk], bfrag[nf][kk], acc[(mg)*2 + mrel][nf], 0, 0, 0)

#define READ_B(tB) \
    _Pragma("unroll") for (int nf = 0; nf < 4; ++nf) \
    _Pragma("unroll") for (int kk = 0; kk < 2; ++kk) \
        bfrag[nf][kk] = lds_frag(tB, wc*64 + nf*16 + ln15, kk*64 + kb16)

#define READ_A(AF, tA, mg) \
    _Pragma("unroll") for (int mrel = 0; mrel < 2; ++mrel) \
    _Pragma("unroll") for (int kk = 0; kk < 2; ++kk) \
        AF[mrel][kk] = lds_frag(tA, wr*128 + (mg)*32 + mrel*16 + ln15, kk*64 + kb16)

// One K-tile, 2 barriers. Chunk-disjoint staging (hazard-proofed):
//   region1: read B(j) all + A mg0,mg1 (chunks 0,2); stage A2(j+1)->other buf
//            (chunks 1,3 of j-1, consumed before bar2(j-1)); MFMA mg0,mg1.
//   BARRIER1  (all waves done with B(j) and A chunks 0,2)
//   region2: read A mg2,mg3 (chunks 1,3); stage B1(j+2)->cB ch0,1,
//            A1(j+2)->cA ch0,2 (disjoint from mg2/mg3 reads), MFMA mg2,
//            stage B2(j+2)->cB ch2,3, MFMA mg3; vmcnt gate; BARRIER2.
// vmcnt: issue order per tile = A2,B1,A1,B2 (8 loads). Steady state before
// gate: {B1,A1,B2}(j+1) + A2(j+1) + {B1,A1,B2}(j+2) = 14; VM(6) retires
// tile j+1 entirely, leaves {B1,A1,B2}(j+2).
#define KTILE_R(bi, jj, SA2, SB, VMN) do { \
    const unsigned short* tA = smem + (bi) * 16384; \
    const unsigned short* tB = smem + 32768 + (bi) * 16384; \
    unsigned short* oA = smem + ((bi) ^ 1) * 16384; \
    unsigned short* cA = smem + (bi) * 16384; \
    unsigned short* cB = smem + 32768 + (bi) * 16384; \
    READ_B(tB); \
    READ_A(af0, tA, 0); \
    if (SA2) { const int ko = ((jj) + 1) << 6; \
        STAGE64(baseA, ko, oA, 1); STAGE64(baseA, ko, oA, 3); } \
    READ_A(af1, tA, 1); \
    __builtin_amdgcn_s_setprio(1); MG_MFMA(0, af0); __builtin_amdgcn_s_setprio(0); \
    __builtin_amdgcn_s_setprio(1); MG_MFMA(1, af1); __builtin_amdgcn_s_setprio(0); \
    BARRIER(); \
    READ_A(af0, tA, 2); \
    if (SB) { const int ko = ((jj) + 2) << 6; \
        STAGE64(baseB, ko, cB, 0); STAGE64(baseB, ko, cB, 1); \
        STAGE64(baseA, ko, cA, 0); STAGE64(baseA, ko, cA, 2); } \
    READ_A(af1, tA, 3); \
    __builtin_amdgcn_s_setprio(1); MG_MFMA(2, af0); __builtin_amdgcn_s_setprio(0); \
    if (SB) { const int ko = ((jj) + 2) << 6; \
        STAGE64(baseB, ko, cB, 2); STAGE64(baseB, ko, cB, 3); } \
    __builtin_amdgcn_s_setprio(1); MG_MFMA(3, af1); __builtin_amdgcn_s_setprio(0); \
    WAIT_VM(VMN); \
    BARRIER(); \
} while (0)

// NT GEMM, 256^2 dbuf, 2-barrier K-tile: C = A[M,K] * Bm[N,K]^T.
// EPI=0: Hout = bf16(silu(C)); EPI=1: fused bias + dynamic causal conv + silu
// with LDS-staged x-window.
template <int EPI>
__global__ __launch_bounds__(512, 2)
void gemm8p(const unsigned short* __restrict__ A,
            const unsigned short* __restrict__ Bm,
            int M, int N, int K,
            unsigned short* __restrict__ Hout,
            const float* __restrict__ bias,
            const float* __restrict__ Xf,
            float* __restrict__ Out) {
    __shared__ __align__(16) unsigned short smem[65536];  // 128 KB

    const int tid  = threadIdx.x;
    const int wave = tid >> 6, lane = tid & 63;
    const int wr = wave >> 2, wc = wave & 3;        // 2M x 4N wave grid
    const int ln15 = lane & 15;
    const int kb16 = (lane >> 4) * 16;              // 16B k-slot within 128B row

    // Region-supertile XCD swizzle (bijective; needs GX%4==0, GY%2==0):
    // xcd = bid&7 owns a (GY/2) x (GX/4) block region, traversed row-major.
    const int GX = gridDim.x, GY = gridDim.y;
    const int bid = blockIdx.y * GX + blockIdx.x;
    const int xcd = bid & 7;
    const int idx = bid >> 3;
    const int W_ = GX >> 2;
    const int rr = idx / W_, cc = idx % W_;
    const int by = (xcd >> 2) * (GY >> 1) + rr;
    const int bx = (xcd & 3) * W_ + cc;
    const int m0 = by * BM, n0 = bx * BN;

    const int nk = K >> 6;   // K-tiles of 64 (=32 here)

    // Per-thread staging offset: lane l -> row wave*8 + (l>>3),
    // slot ((l&7)^((l>>3)&7)) (inverse swizzle).
    const int srow = (wave << 3) + (lane >> 3);
    const int scol = (((lane & 7) ^ ((lane >> 3) & 7)) << 3);  // ushort units
    const size_t soff = (size_t)srow * K + scol;
    const unsigned short* baseA = A + (size_t)m0 * K;
    const unsigned short* baseB = Bm + (size_t)n0 * K;

    f32x4 acc[8][4];
#pragma unroll
    for (int i = 0; i < 8; ++i)
#pragma unroll
        for (int j = 0; j < 4; ++j) acc[i][j] = (f32x4)0.0f;

    bf16x8 bfrag[4][2], af0[2][2], af1[2][2];

    // ---- prologue: tile 0 all 4 halves + tile 1's B1,A1,B2 (A2(1) in tile0) ----
    {
        unsigned short* dA0 = smem;
        unsigned short* dB0 = smem + 32768;
        unsigned short* dA1 = smem + 16384;
        unsigned short* dB1 = smem + 49152;
        STAGE64(baseB, 0, dB0, 0); STAGE64(baseB, 0, dB0, 1);
        STAGE64(baseB, 0, dB0, 2); STAGE64(baseB, 0, dB0, 3);
        STAGE64(baseA, 0, dA0, 0); STAGE64(baseA, 0, dA0, 1);
        STAGE64(baseA, 0, dA0, 2); STAGE64(baseA, 0, dA0, 3);
        STAGE64(baseB, BKT, dB1, 0); STAGE64(baseB, BKT, dB1, 1);  // B1(1)
        STAGE64(baseA, BKT, dA1, 0); STAGE64(baseA, BKT, dA1, 2);  // A1(1)
        STAGE64(baseB, BKT, dB1, 2); STAGE64(baseB, BKT, dB1, 3);  // B2(1)
    }
    WAIT_VM(6);   // tile 0 landed; tile 1's 3 halves in flight
    BARRIER();

    // ---- main loop: tiles 0..nk-3 steady; last two tiles peeled ----
    for (int it = 0; it < (nk >> 1) - 1; ++it) {
        const int j = it << 1;
        KTILE_R(0, j,     1, 1, 6);
        KTILE_R(1, j + 1, 1, 1, 6);
    }
    KTILE_R(0, nk - 2, 1, 0, 0);   // stage only A2(nk-1); drain
    KTILE_R(1, nk - 1, 0, 0, 0);

    // ---- epilogue ----
    if (EPI == 0) {
#pragma unroll
        for (int mf = 0; mf < 8; ++mf) {
            int rowb = m0 + wr * 128 + mf * 16 + (lane >> 4) * 4;
#pragma unroll
            for (int nf = 0; nf < 4; ++nf) {
                int col = n0 + wc * 64 + nf * 16 + ln15;
#pragma unroll
                for (int r2 = 0; r2 < 4; ++r2) {
                    Hout[(size_t)(rowb + r2) * N + col] = f2bf(silu_f(acc[mf][nf][r2]));
                }
            }
        }
    } else {
        // Stage x-window into LDS: rows ts = t0-3 .. t0+255 (259), 64 d cols.
        const int t0 = m0 & (T_DIM - 1);
        const int bidx = m0 >> 12;
        const int dbase = n0 >> 2;
        float* Xw = reinterpret_cast<float*>(smem);   // [259][XW_STRIDE]
        for (int idx2 = tid; idx2 < 259 * 16; idx2 += 512) {
            int rw = idx2 >> 4, q = (idx2 & 15) << 2;
            int ts = t0 - 3 + rw;
            float4 v = make_float4(0.f, 0.f, 0.f, 0.f);
            if (ts >= 0)
                v = *reinterpret_cast<const float4*>(
                    &Xf[((size_t)bidx * T_DIM + ts) * D_DIM + dbase + q]);
            float* p = &Xw[rw * XW_STRIDE + q];
            p[0] = v.x; p[1] = v.y; p[2] = v.z; p[3] = v.w;
        }
        __syncthreads();

        // k = C + bias; out[b,t,d] = silu(sum_w x[b,t-3+w,d] * k[t, d*4+w])
        // col -> (d = col>>2, w = col&3); 4-lane butterfly sums over w.
        const int dl = wc * 16 + (ln15 >> 2);   // + nf*4 below
        const int w = lane & 3;
#pragma unroll
        for (int mf = 0; mf < 8; ++mf) {
            int lrow0 = wr * 128 + mf * 16 + (lane >> 4) * 4;
#pragma unroll
            for (int nf = 0; nf < 4; ++nf) {
                int col = n0 + wc * 64 + nf * 16 + ln15;
                int d = col >> 2;
                float bv = bias[col];
#pragma unroll
                for (int r2 = 0; r2 < 4; ++r2) {
                    int lrow = lrow0 + r2;
                    float v = acc[mf][nf][r2] + bv;
                    float xv = Xw[(lrow + w) * XW_STRIDE + dl + nf * 4];
                    float p = v * xv;
                    p += __shfl_xor(p, 1);
                    p += __shfl_xor(p, 2);
                    if ((lane & 3) == 0) {
                        Out[((size_t)bidx * T_DIM + (t0 + lrow)) * D_DIM + d] = silu_f(p);
                    }
                }
            }
        }
    }
}

extern "C" void kernel_launch(void* const* d_in, const int* in_sizes, int n_in,
                              void* d_out, int out_size, void* d_ws, size_t ws_size,
                              hipStream_t stream) {
    const float* x    = (const float*)d_in[0];  // [B,T,D]
    const float* w1   = (const float*)d_in[1];  // [H,D]
    const float* w2w  = (const float*)d_in[2];  // [D*W,H]
    const float* w2b  = (const float*)d_in[3];  // [D*W]
    float* out = (float*)d_out;

    // Workspace: ws0 = xb [M,D] bf16 (later reused for w2wb [N2,H] bf16),
    //            ws1 = w1b [H,D] bf16, ws2 = hb [M,H] bf16.
    unsigned short* ws0 = (unsigned short*)d_ws;
    unsigned short* ws1 = ws0 + (size_t)M_DIM * D_DIM;
    unsigned short* ws2 = ws1 + (size_t)H_DIM * D_DIM;

    const int CT = 256;
    {
        int n4 = (M_DIM * D_DIM) / 4;
        cvt_f32_to_bf16<<<(n4 + CT - 1) / CT, CT, 0, stream>>>(x, ws0, n4);
    }
    {
        int n4 = (H_DIM * D_DIM) / 4;
        cvt_f32_to_bf16<<<(n4 + CT - 1) / CT, CT, 0, stream>>>(w1, ws1, n4);
    }
    // GEMM1: hb = silu(xb @ w1b^T)  [8192, 2048]
    gemm8p<0><<<dim3(H_DIM / BN, M_DIM / BM), 512, 0, stream>>>(
        ws0, ws1, M_DIM, H_DIM, D_DIM, ws2, nullptr, nullptr, nullptr);
    // convert w2_w into ws0 (xb now dead)
    {
        int n4 = (N2_DIM * H_DIM) / 4;
        cvt_f32_to_bf16<<<(n4 + CT - 1) / CT, CT, 0, stream>>>(w2w, ws0, n4);
    }
    // GEMM2 + fused bias/conv/silu -> out
    gemm8p<1><<<dim3(N2_DIM / BN, M_DIM / BM), 512, 0, stream>>>(
        ws2, ws0, M_DIM, N2_DIM, H_DIM, nullptr, w2b, x, out);
}

// Round 9
// 369.549 us; speedup vs baseline: 1.1089x; 1.0873x over previous
//
#include <hip/hip_runtime.h>
#include <hip/hip_bf16.h>
#include <math.h>

// Problem constants (B=2, T=4096, D=2048, H=2048, W=4)
#define B_DIM 2
#define T_DIM 4096
#define D_DIM 2048
#define H_DIM 2048
#define W_K   4
#define M_DIM (B_DIM * T_DIM)   // 8192 tokens
#define N2_DIM (D_DIM * W_K)    // 8192

typedef __bf16 bf16x8 __attribute__((ext_vector_type(8)));
typedef float  f32x4  __attribute__((ext_vector_type(4)));

// 256x256 tile, K-tile 64, double-buffered, 8 waves (2M x 4N).
// 2 barriers per K-tile; compiler-scheduled ds_read/MFMA overlap.
// B-fragment columns PERMUTED (row = ln15*4 + nf) so the conv epilogue's
// w-sum is lane-local (no shfl) and GEMM1's 4 cols/lane are contiguous.
#define BM 256
#define BN 256
#define BKT 64
#define XW_STRIDE 68   // f32 stride for epilogue x-window (2-way-free banks)

__device__ __forceinline__ unsigned short f2bf(float f) {
    unsigned int u = __float_as_uint(f);
    unsigned int r = (u + 0x7FFFu + ((u >> 16) & 1u)) >> 16;  // RNE
    return (unsigned short)r;
}

__device__ __forceinline__ float silu_f(float v) {
    return v / (1.0f + __expf(-v));
}

__global__ void cvt_f32_to_bf16(const float* __restrict__ in,
                                unsigned short* __restrict__ out, int n4) {
    int i = blockIdx.x * blockDim.x + threadIdx.x;
    if (i >= n4) return;
    float4 v = reinterpret_cast<const float4*>(in)[i];
    ushort4 o;
    o.x = f2bf(v.x); o.y = f2bf(v.y); o.z = f2bf(v.z); o.w = f2bf(v.w);
    reinterpret_cast<ushort4*>(out)[i] = o;
}

// LDS tile: [256 rows][64 bf16] = 128 B/row, XOR swizzle on the 16B slot:
//   slot_xor s2(r) = (r&7) ^ ((r>>3)&7)
// Derivation: A-reads use 16 consecutive rows (r&7 covers 0-7 twice, r>>3
// two values) -> all 8 slots x2 = 2-way (free). Permuted B-reads use rows
// 4p+nf: s2 = (nf+4(p&1))^(p>>1) -> all 8 slots x2 = 2-way (free).
__device__ __forceinline__ bf16x8 lds_frag(const unsigned short* buf, int r, int kb) {
    int sx = (((r & 7) ^ ((r >> 3) & 7)) << 4);
    int lin = r * 128 + (kb ^ sx);
    return *reinterpret_cast<const bf16x8*>(reinterpret_cast<const char*>(buf) + lin);
}

#define BARRIER()    __builtin_amdgcn_s_barrier()
#define WAIT_VM(N)   asm volatile("s_waitcnt vmcnt(" #N ")" ::: "memory")

// Stage one 8KB chunk (64 rows x 64 cols bf16) of a K-tile into LDS.
// Dest = wave-uniform base + lane*16 (linear); swizzle applied by inverse-
// permuting the per-lane GLOBAL source (rule #21, XOR involution).
// Lane l -> row chunk*64 + wave*8 + (l>>3); phys slot l&7; logical slot
// (l&7) ^ s2(row) = (l&7) ^ (l>>3) ^ wave.
#define STAGE64(basePtr, ko, dstUshort, chunk) \
    __builtin_amdgcn_global_load_lds( \
        (const __attribute__((address_space(1))) void*)((basePtr) + soff + (size_t)(chunk) * 64 * K + (ko)), \
        (__attribute__((address_space(3))) void*)(reinterpret_cast<char*>(dstUshort) + ((chunk) << 13) + (wave << 10)), \
        16, 0, 0)

// 16 MFMA for one M-group: 2 Mfrags x 4 Nfrags x 2 K-steps.
#define MG_MFMA(mg, AF) \
    _Pragma("unroll") for (int kk = 0; kk < 2; ++kk) \
    _Pragma("unroll") for (int mrel = 0; mrel < 2; ++mrel) \
    _Pragma("unroll") for (int nf = 0; nf < 4; ++nf) \
        acc[(mg)*2 + mrel][nf] = __builtin_amdgcn_mfma_f32_16x16x32_bf16( \
            AF[mrel][kk], bfrag[nf][kk], acc[(mg)*2 + mrel][nf], 0, 0, 0)

// PERMUTED B read: fragment nf holds output cols {p*4+nf : p=0..15}
// (lane p gets col wc*64 + p*4 + nf) -> per-lane w-group for the conv.
#define READ_B(tB) \
    _Pragma("unroll") for (int nf = 0; nf < 4; ++nf) \
    _Pragma("unroll") for (int kk = 0; kk < 2; ++kk) \
        bfrag[nf][kk] = lds_frag(tB, wc*64 + ln15*4 + nf, kk*64 + kb16)

#define READ_A(AF, tA, mg) \
    _Pragma("unroll") for (int mrel = 0; mrel < 2; ++mrel) \
    _Pragma("unroll") for (int kk = 0; kk < 2; ++kk) \
        AF[mrel][kk] = lds_frag(tA, wr*128 + (mg)*32 + mrel*16 + ln15, kk*64 + kb16)

// One K-tile, 2 barriers (hazard proof unchanged from R7).
// vmcnt: issue order per tile = A2,B1,A1,B2 (8 loads); steady outstanding 14;
// VM(6) retires tile j+1 entirely, leaves {B1,A1,B2}(j+2).
#define KTILE_R(bi, jj, SA2, SB, VMN) do { \
    const unsigned short* tA = smem + (bi) * 16384; \
    const unsigned short* tB = smem + 32768 + (bi) * 16384; \
    unsigned short* oA = smem + ((bi) ^ 1) * 16384; \
    unsigned short* cA = smem + (bi) * 16384; \
    unsigned short* cB = smem + 32768 + (bi) * 16384; \
    READ_B(tB); \
    READ_A(af0, tA, 0); \
    if (SA2) { const int ko = ((jj) + 1) << 6; \
        STAGE64(baseA, ko, oA, 1); STAGE64(baseA, ko, oA, 3); } \
    READ_A(af1, tA, 1); \
    __builtin_amdgcn_s_setprio(1); MG_MFMA(0, af0); __builtin_amdgcn_s_setprio(0); \
    __builtin_amdgcn_s_setprio(1); MG_MFMA(1, af1); __builtin_amdgcn_s_setprio(0); \
    BARRIER(); \
    READ_A(af0, tA, 2); \
    if (SB) { const int ko = ((jj) + 2) << 6; \
        STAGE64(baseB, ko, cB, 0); STAGE64(baseB, ko, cB, 1); \
        STAGE64(baseA, ko, cA, 0); STAGE64(baseA, ko, cA, 2); } \
    READ_A(af1, tA, 3); \
    __builtin_amdgcn_s_setprio(1); MG_MFMA(2, af0); __builtin_amdgcn_s_setprio(0); \
    if (SB) { const int ko = ((jj) + 2) << 6; \
        STAGE64(baseB, ko, cB, 2); STAGE64(baseB, ko, cB, 3); } \
    __builtin_amdgcn_s_setprio(1); MG_MFMA(3, af1); __builtin_amdgcn_s_setprio(0); \
    WAIT_VM(VMN); \
    BARRIER(); \
} while (0)

// NT GEMM, 256^2 dbuf, 2-barrier K-tile: C = A[M,K] * Bm[N,K]^T.
// EPI=0: Hout = bf16(silu(C)) (ushort4-packed stores);
// EPI=1: fused bias + dynamic causal conv + silu, shfl-free lane-local w-sum.
template <int EPI>
__global__ __launch_bounds__(512, 2)
void gemm8p(const unsigned short* __restrict__ A,
            const unsigned short* __restrict__ Bm,
            int M, int N, int K,
            unsigned short* __restrict__ Hout,
            const float* __restrict__ bias,
            const float* __restrict__ Xf,
            float* __restrict__ Out) {
    __shared__ __align__(16) unsigned short smem[65536];  // 128 KB

    const int tid  = threadIdx.x;
    const int wave = tid >> 6, lane = tid & 63;
    const int wr = wave >> 2, wc = wave & 3;        // 2M x 4N wave grid
    const int ln15 = lane & 15;
    const int kb16 = (lane >> 4) * 16;              // 16B k-slot within 128B row

    // Region-supertile XCD swizzle (bijective; needs GX%4==0, GY%2==0)
    const int GX = gridDim.x, GY = gridDim.y;
    const int bid = blockIdx.y * GX + blockIdx.x;
    const int xcd = bid & 7;
    const int idx = bid >> 3;
    const int W_ = GX >> 2;
    const int rr = idx / W_, cc = idx % W_;
    const int by = (xcd >> 2) * (GY >> 1) + rr;
    const int bx = (xcd & 3) * W_ + cc;
    const int m0 = by * BM, n0 = bx * BN;

    const int nk = K >> 6;   // K-tiles of 64 (=32 here)

    // Per-thread staging offset (inverse swizzle, see STAGE64 comment).
    const int srow = (wave << 3) + (lane >> 3);
    const int scol = (((lane & 7) ^ (lane >> 3) ^ wave) << 3);  // ushort units
    const size_t soff = (size_t)srow * K + scol;
    const unsigned short* baseA = A + (size_t)m0 * K;
    const unsigned short* baseB = Bm + (size_t)n0 * K;

    f32x4 acc[8][4];
#pragma unroll
    for (int i = 0; i < 8; ++i)
#pragma unroll
        for (int j = 0; j < 4; ++j) acc[i][j] = (f32x4)0.0f;

    bf16x8 bfrag[4][2], af0[2][2], af1[2][2];

    // ---- prologue: tile 0 all 4 halves + tile 1's B1,A1,B2 (A2(1) in tile0) ----
    {
        unsigned short* dA0 = smem;
        unsigned short* dB0 = smem + 32768;
        unsigned short* dA1 = smem + 16384;
        unsigned short* dB1 = smem + 49152;
        STAGE64(baseB, 0, dB0, 0); STAGE64(baseB, 0, dB0, 1);
        STAGE64(baseB, 0, dB0, 2); STAGE64(baseB, 0, dB0, 3);
        STAGE64(baseA, 0, dA0, 0); STAGE64(baseA, 0, dA0, 1);
        STAGE64(baseA, 0, dA0, 2); STAGE64(baseA, 0, dA0, 3);
        STAGE64(baseB, BKT, dB1, 0); STAGE64(baseB, BKT, dB1, 1);  // B1(1)
        STAGE64(baseA, BKT, dA1, 0); STAGE64(baseA, BKT, dA1, 2);  // A1(1)
        STAGE64(baseB, BKT, dB1, 2); STAGE64(baseB, BKT, dB1, 3);  // B2(1)
    }
    WAIT_VM(6);   // tile 0 landed; tile 1's 3 halves in flight
    BARRIER();

    // ---- main loop: tiles 0..nk-3 steady; last two tiles peeled ----
    for (int it = 0; it < (nk >> 1) - 1; ++it) {
        const int j = it << 1;
        KTILE_R(0, j,     1, 1, 6);
        KTILE_R(1, j + 1, 1, 1, 6);
    }
    KTILE_R(0, nk - 2, 1, 0, 0);   // stage only A2(nk-1); drain
    KTILE_R(1, nk - 1, 0, 0, 0);

    // ---- epilogue ----
    // Lane p (=ln15) holds, across nf=0..3, output cols wc*64 + p*4 + nf.
    if (EPI == 0) {
        const size_t colbase = n0 + wc * 64 + ln15 * 4;
#pragma unroll
        for (int mf = 0; mf < 8; ++mf) {
            int rowb = m0 + wr * 128 + mf * 16 + (lane >> 4) * 4;
#pragma unroll
            for (int r2 = 0; r2 < 4; ++r2) {
                ushort4 h4;
                h4.x = f2bf(silu_f(acc[mf][0][r2]));
                h4.y = f2bf(silu_f(acc[mf][1][r2]));
                h4.z = f2bf(silu_f(acc[mf][2][r2]));
                h4.w = f2bf(silu_f(acc[mf][3][r2]));
                *reinterpret_cast<ushort4*>(&Hout[(size_t)(rowb + r2) * N + colbase]) = h4;
            }
        }
    } else {
        // Stage x-window into LDS: rows ts = t0-3 .. t0+255 (259), 64 d cols.
        const int t0 = m0 & (T_DIM - 1);
        const int bidx = m0 >> 12;
        const int dbase = n0 >> 2;
        float* Xw = reinterpret_cast<float*>(smem);   // [259][XW_STRIDE]
        for (int idx2 = tid; idx2 < 259 * 16; idx2 += 512) {
            int rw = idx2 >> 4, q = (idx2 & 15) << 2;
            int ts = t0 - 3 + rw;
            float4 v = make_float4(0.f, 0.f, 0.f, 0.f);
            if (ts >= 0)
                v = *reinterpret_cast<const float4*>(
                    &Xf[((size_t)bidx * T_DIM + ts) * D_DIM + dbase + q]);
            float* p = &Xw[rw * XW_STRIDE + q];
            p[0] = v.x; p[1] = v.y; p[2] = v.z; p[3] = v.w;
        }
        __syncthreads();

        // out[b,t,d] = silu(sum_w x[b,t-3+w,d] * (C+bias)[t, d*4+w]);
        // lane-local: d = dbase + wc*16 + p, w = nf. No shfl.
        const int dloc = wc * 16 + ln15;
        const float4 bias4 = *reinterpret_cast<const float4*>(
            &bias[n0 + wc * 64 + ln15 * 4]);
#pragma unroll
        for (int mf = 0; mf < 8; ++mf) {
            int lrow0 = wr * 128 + mf * 16 + (lane >> 4) * 4;
            float xr[7];
#pragma unroll
            for (int q = 0; q < 7; ++q)
                xr[q] = Xw[(lrow0 + q) * XW_STRIDE + dloc];
#pragma unroll
            for (int r2 = 0; r2 < 4; ++r2) {
                float v = (acc[mf][0][r2] + bias4.x) * xr[r2 + 0];
                v      += (acc[mf][1][r2] + bias4.y) * xr[r2 + 1];
                v      += (acc[mf][2][r2] + bias4.z) * xr[r2 + 2];
                v      += (acc[mf][3][r2] + bias4.w) * xr[r2 + 3];
                int lrow = lrow0 + r2;
                Out[((size_t)bidx * T_DIM + (t0 + lrow)) * D_DIM + dbase + dloc] = silu_f(v);
            }
        }
    }
}

extern "C" void kernel_launch(void* const* d_in, const int* in_sizes, int n_in,
                              void* d_out, int out_size, void* d_ws, size_t ws_size,
                              hipStream_t stream) {
    const float* x    = (const float*)d_in[0];  // [B,T,D]
    const float* w1   = (const float*)d_in[1];  // [H,D]
    const float* w2w  = (const float*)d_in[2];  // [D*W,H]
    const float* w2b  = (const float*)d_in[3];  // [D*W]
    float* out = (float*)d_out;

    // Workspace: ws0 = xb [M,D] bf16 (later reused for w2wb [N2,H] bf16),
    //            ws1 = w1b [H,D] bf16, ws2 = hb [M,H] bf16.
    unsigned short* ws0 = (unsigned short*)d_ws;
    unsigned short* ws1 = ws0 + (size_t)M_DIM * D_DIM;
    unsigned short* ws2 = ws1 + (size_t)H_DIM * D_DIM;

    const int CT = 256;
    {
        int n4 = (M_DIM * D_DIM) / 4;
        cvt_f32_to_bf16<<<(n4 + CT - 1) / CT, CT, 0, stream>>>(x, ws0, n4);
    }
    {
        int n4 = (H_DIM * D_DIM) / 4;
        cvt_f32_to_bf16<<<(n4 + CT - 1) / CT, CT, 0, stream>>>(w1, ws1, n4);
    }
    // GEMM1: hb = silu(xb @ w1b^T)  [8192, 2048]
    gemm8p<0><<<dim3(H_DIM / BN, M_DIM / BM), 512, 0, stream>>>(
        ws0, ws1, M_DIM, H_DIM, D_DIM, ws2, nullptr, nullptr, nullptr);
    // convert w2_w into ws0 (xb now dead)
    {
        int n4 = (N2_DIM * H_DIM) / 4;
        cvt_f32_to_bf16<<<(n4 + CT - 1) / CT, CT, 0, stream>>>(w2w, ws0, n4);
    }
    // GEMM2 + fused bias/conv/silu -> out
    gemm8p<1><<<dim3(N2_DIM / BN, M_DIM / BM), 512, 0, stream>>>(
        ws2, ws0, M_DIM, N2_DIM, H_DIM, nullptr, w2b, x, out);
}

// Round 10
// 339.649 us; speedup vs baseline: 1.2065x; 1.0880x over previous
//
#include <hip/hip_runtime.h>
#include <hip/hip_bf16.h>
#include <math.h>

// Problem constants (B=2, T=4096, D=2048, H=2048, W=4)
#define B_DIM 2
#define T_DIM 4096
#define D_DIM 2048
#define H_DIM 2048
#define W_K   4
#define M_DIM (B_DIM * T_DIM)   // 8192 tokens
#define N2_DIM (D_DIM * W_K)    // 8192

typedef __bf16 bf16x8 __attribute__((ext_vector_type(8)));
typedef float  f32x4  __attribute__((ext_vector_type(4)));

// 256x256 tile, K-tile 64, double-buffered, 8 waves (2M x 4N).
// 2 barriers per K-tile; compiler-scheduled ds_read/MFMA overlap.
// B is stored ROW-PERMUTED in LDS (band row 16*nf+p holds global row 4p+nf)
// so the conv epilogue's w-sum is lane-local while the ds_read pattern stays
// the R7-verified conflict-free consecutive-row form.
#define BM 256
#define BN 256
#define BKT 64
#define XW_STRIDE 68   // f32 stride for epilogue x-window (2-way-free banks)

__device__ __forceinline__ unsigned short f2bf(float f) {
    unsigned int u = __float_as_uint(f);
    unsigned int r = (u + 0x7FFFu + ((u >> 16) & 1u)) >> 16;  // RNE
    return (unsigned short)r;
}

__device__ __forceinline__ float silu_f(float v) {
    return v / (1.0f + __expf(-v));
}

__global__ void cvt_f32_to_bf16(const float* __restrict__ in,
                                unsigned short* __restrict__ out, int n4) {
    int i = blockIdx.x * blockDim.x + threadIdx.x;
    if (i >= n4) return;
    float4 v = reinterpret_cast<const float4*>(in)[i];
    ushort4 o;
    o.x = f2bf(v.x); o.y = f2bf(v.y); o.z = f2bf(v.z); o.w = f2bf(v.w);
    reinterpret_cast<ushort4*>(out)[i] = o;
}

// LDS tile: [256 rows][64 bf16] = 128 B/row, XOR swizzle (R7-verified, 0 conflicts):
//   phys = r*128 + (kb ^ ((r&7)<<4))
// Reads use 16 consecutive rows per fragment -> slots (r&7) cover all 8 x2
// = exact 2-way bank aliasing (free, m136).
__device__ __forceinline__ bf16x8 lds_frag(const unsigned short* buf, int r, int kb) {
    int lin = r * 128 + (kb ^ ((r & 7) << 4));
    return *reinterpret_cast<const bf16x8*>(reinterpret_cast<const char*>(buf) + lin);
}

#define BARRIER()    __builtin_amdgcn_s_barrier()
#define WAIT_VM(N)   asm volatile("s_waitcnt vmcnt(" #N ")" ::: "memory")

// Stage one 8KB chunk (64 rows x 64 cols bf16) of a K-tile into LDS.
// Dest = wave-uniform base + lane*16 (linear); swizzle applied by inverse-
// permuting the per-lane GLOBAL source (rule #21); for B additionally the
// within-band ROW permutation pi(r) = ((r&15)<<2)|(r>>4) is applied to the
// global source row, so LDS band-row 16*nf+p holds global row 4p+nf.
#define STAGE64(basePtr, soffX, ko, dstUshort, chunk) \
    __builtin_amdgcn_global_load_lds( \
        (const __attribute__((address_space(1))) void*)((basePtr) + (soffX) + (size_t)(chunk) * 64 * K + (ko)), \
        (__attribute__((address_space(3))) void*)(reinterpret_cast<char*>(dstUshort) + ((chunk) << 13) + (wave << 10)), \
        16, 0, 0)

// 16 MFMA for one M-group: 2 Mfrags x 4 Nfrags x 2 K-steps.
#define MG_MFMA(mg, AF) \
    _Pragma("unroll") for (int kk = 0; kk < 2; ++kk) \
    _Pragma("unroll") for (int mrel = 0; mrel < 2; ++mrel) \
    _Pragma("unroll") for (int nf = 0; nf < 4; ++nf) \
        acc[(mg)*2 + mrel][nf] = __builtin_amdgcn_mfma_f32_16x16x32_bf16( \
            AF[mrel][kk], bfrag[nf][kk], acc[(mg)*2 + mrel][nf], 0, 0, 0)

// B read: consecutive rows (R7 pattern, conflict-free). Because of the
// staging row-permutation, fragment nf lane p holds global col 4p+nf
// (within the wave's 64-col band) -> lane-local w-group for the conv.
#define READ_B(tB) \
    _Pragma("unroll") for (int nf = 0; nf < 4; ++nf) \
    _Pragma("unroll") for (int kk = 0; kk < 2; ++kk) \
        bfrag[nf][kk] = lds_frag(tB, wc*64 + nf*16 + ln15, kk*64 + kb16)

#define READ_A(AF, tA, mg) \
    _Pragma("unroll") for (int mrel = 0; mrel < 2; ++mrel) \
    _Pragma("unroll") for (int kk = 0; kk < 2; ++kk) \
        AF[mrel][kk] = lds_frag(tA, wr*128 + (mg)*32 + mrel*16 + ln15, kk*64 + kb16)

// One K-tile, 2 barriers (hazard proof as R7/R8).
// vmcnt: issue order per tile = A2,B1,A1,B2 (8 loads); steady outstanding 14;
// VM(6) retires tile j+1 entirely, leaves {B1,A1,B2}(j+2).
#define KTILE_R(bi, jj, SA2, SB, VMN) do { \
    const unsigned short* tA = smem + (bi) * 16384; \
    const unsigned short* tB = smem + 32768 + (bi) * 16384; \
    unsigned short* oA = smem + ((bi) ^ 1) * 16384; \
    unsigned short* cA = smem + (bi) * 16384; \
    unsigned short* cB = smem + 32768 + (bi) * 16384; \
    READ_B(tB); \
    READ_A(af0, tA, 0); \
    if (SA2) { const int ko = ((jj) + 1) << 6; \
        STAGE64(baseA, soffA, ko, oA, 1); STAGE64(baseA, soffA, ko, oA, 3); } \
    READ_A(af1, tA, 1); \
    __builtin_amdgcn_s_setprio(1); MG_MFMA(0, af0); __builtin_amdgcn_s_setprio(0); \
    __builtin_amdgcn_s_setprio(1); MG_MFMA(1, af1); __builtin_amdgcn_s_setprio(0); \
    BARRIER(); \
    READ_A(af0, tA, 2); \
    if (SB) { const int ko = ((jj) + 2) << 6; \
        STAGE64(baseB, soffB, ko, cB, 0); STAGE64(baseB, soffB, ko, cB, 1); \
        STAGE64(baseA, soffA, ko, cA, 0); STAGE64(baseA, soffA, ko, cA, 2); } \
    READ_A(af1, tA, 3); \
    __builtin_amdgcn_s_setprio(1); MG_MFMA(2, af0); __builtin_amdgcn_s_setprio(0); \
    if (SB) { const int ko = ((jj) + 2) << 6; \
        STAGE64(baseB, soffB, ko, cB, 2); STAGE64(baseB, soffB, ko, cB, 3); } \
    __builtin_amdgcn_s_setprio(1); MG_MFMA(3, af1); __builtin_amdgcn_s_setprio(0); \
    WAIT_VM(VMN); \
    BARRIER(); \
} while (0)

// NT GEMM, 256^2 dbuf, 2-barrier K-tile: C = A[M,K] * Bm[N,K]^T.
// EPI=0: Hout = bf16(silu(C)) (ushort4-packed stores);
// EPI=1: fused bias + dynamic causal conv + silu, shfl-free lane-local w-sum.
template <int EPI>
__global__ __launch_bounds__(512, 2)
void gemm8p(const unsigned short* __restrict__ A,
            const unsigned short* __restrict__ Bm,
            int M, int N, int K,
            unsigned short* __restrict__ Hout,
            const float* __restrict__ bias,
            const float* __restrict__ Xf,
            float* __restrict__ Out) {
    __shared__ __align__(16) unsigned short smem[65536];  // 128 KB

    const int tid  = threadIdx.x;
    const int wave = tid >> 6, lane = tid & 63;
    const int wr = wave >> 2, wc = wave & 3;        // 2M x 4N wave grid
    const int ln15 = lane & 15;
    const int kb16 = (lane >> 4) * 16;              // 16B k-slot within 128B row

    // Region-supertile XCD swizzle (bijective; needs GX%4==0, GY%2==0)
    const int GX = gridDim.x, GY = gridDim.y;
    const int bid = blockIdx.y * GX + blockIdx.x;
    const int xcd = bid & 7;
    const int idx = bid >> 3;
    const int W_ = GX >> 2;
    const int rr = idx / W_, cc = idx % W_;
    const int by = (xcd >> 2) * (GY >> 1) + rr;
    const int bx = (xcd & 3) * W_ + cc;
    const int m0 = by * BM, n0 = bx * BN;

    const int nk = K >> 6;   // K-tiles of 64 (=32 here)

    // Per-thread staging offsets. Phys LDS row (within 64-row chunk):
    // srow = wave*8 + lane/8; phys slot lane&7; logical col slot =
    // (lane&7) ^ s2(srow) = (lane&7) ^ (lane>>3)   [s2(r) = r&7].
    // A: identity rows. B: within-band row permutation pi(srow).
    const int srow = (wave << 3) + (lane >> 3);
    const int scol = (((lane & 7) ^ (lane >> 3)) << 3);  // ushort units
    const size_t soffA = (size_t)srow * K + scol;
    const int prow = ((srow & 15) << 2) | (srow >> 4);   // pi(srow)
    const size_t soffB = (size_t)prow * K + scol;
    const unsigned short* baseA = A + (size_t)m0 * K;
    const unsigned short* baseB = Bm + (size_t)n0 * K;

    f32x4 acc[8][4];
#pragma unroll
    for (int i = 0; i < 8; ++i)
#pragma unroll
        for (int j = 0; j < 4; ++j) acc[i][j] = (f32x4)0.0f;

    bf16x8 bfrag[4][2], af0[2][2], af1[2][2];

    // ---- prologue: tile 0 all 4 halves + tile 1's B1,A1,B2 (A2(1) in tile0) ----
    {
        unsigned short* dA0 = smem;
        unsigned short* dB0 = smem + 32768;
        unsigned short* dA1 = smem + 16384;
        unsigned short* dB1 = smem + 49152;
        STAGE64(baseB, soffB, 0, dB0, 0); STAGE64(baseB, soffB, 0, dB0, 1);
        STAGE64(baseB, soffB, 0, dB0, 2); STAGE64(baseB, soffB, 0, dB0, 3);
        STAGE64(baseA, soffA, 0, dA0, 0); STAGE64(baseA, soffA, 0, dA0, 1);
        STAGE64(baseA, soffA, 0, dA0, 2); STAGE64(baseA, soffA, 0, dA0, 3);
        STAGE64(baseB, soffB, BKT, dB1, 0); STAGE64(baseB, soffB, BKT, dB1, 1);  // B1(1)
        STAGE64(baseA, soffA, BKT, dA1, 0); STAGE64(baseA, soffA, BKT, dA1, 2);  // A1(1)
        STAGE64(baseB, soffB, BKT, dB1, 2); STAGE64(baseB, soffB, BKT, dB1, 3);  // B2(1)
    }
    WAIT_VM(6);   // tile 0 landed; tile 1's 3 halves in flight
    BARRIER();

    // ---- main loop: tiles 0..nk-3 steady; last two tiles peeled ----
    for (int it = 0; it < (nk >> 1) - 1; ++it) {
        const int j = it << 1;
        KTILE_R(0, j,     1, 1, 6);
        KTILE_R(1, j + 1, 1, 1, 6);
    }
    KTILE_R(0, nk - 2, 1, 0, 0);   // stage only A2(nk-1); drain
    KTILE_R(1, nk - 1, 0, 0, 0);

    // ---- epilogue ----
    // Lane p (=ln15) holds, across nf=0..3, output cols wc*64 + p*4 + nf.
    if (EPI == 0) {
        const size_t colbase = n0 + wc * 64 + ln15 * 4;
#pragma unroll
        for (int mf = 0; mf < 8; ++mf) {
            int rowb = m0 + wr * 128 + mf * 16 + (lane >> 4) * 4;
#pragma unroll
            for (int r2 = 0; r2 < 4; ++r2) {
                ushort4 h4;
                h4.x = f2bf(silu_f(acc[mf][0][r2]));
                h4.y = f2bf(silu_f(acc[mf][1][r2]));
                h4.z = f2bf(silu_f(acc[mf][2][r2]));
                h4.w = f2bf(silu_f(acc[mf][3][r2]));
                *reinterpret_cast<ushort4*>(&Hout[(size_t)(rowb + r2) * N + colbase]) = h4;
            }
        }
    } else {
        // Stage x-window into LDS: rows ts = t0-3 .. t0+255 (259), 64 d cols.
        const int t0 = m0 & (T_DIM - 1);
        const int bidx = m0 >> 12;
        const int dbase = n0 >> 2;
        float* Xw = reinterpret_cast<float*>(smem);   // [259][XW_STRIDE]
        for (int idx2 = tid; idx2 < 259 * 16; idx2 += 512) {
            int rw = idx2 >> 4, q = (idx2 & 15) << 2;
            int ts = t0 - 3 + rw;
            float4 v = make_float4(0.f, 0.f, 0.f, 0.f);
            if (ts >= 0)
                v = *reinterpret_cast<const float4*>(
                    &Xf[((size_t)bidx * T_DIM + ts) * D_DIM + dbase + q]);
            float* p = &Xw[rw * XW_STRIDE + q];
            p[0] = v.x; p[1] = v.y; p[2] = v.z; p[3] = v.w;
        }
        __syncthreads();

        // out[b,t,d] = silu(sum_w x[b,t-3+w,d] * (C+bias)[t, d*4+w]);
        // lane-local: d = dbase + wc*16 + p, w = nf. No shfl.
        const int dloc = wc * 16 + ln15;
        const float4 bias4 = *reinterpret_cast<const float4*>(
            &bias[n0 + wc * 64 + ln15 * 4]);
#pragma unroll
        for (int mf = 0; mf < 8; ++mf) {
            int lrow0 = wr * 128 + mf * 16 + (lane >> 4) * 4;
            float xr[7];
#pragma unroll
            for (int q = 0; q < 7; ++q)
                xr[q] = Xw[(lrow0 + q) * XW_STRIDE + dloc];
#pragma unroll
            for (int r2 = 0; r2 < 4; ++r2) {
                float v = (acc[mf][0][r2] + bias4.x) * xr[r2 + 0];
                v      += (acc[mf][1][r2] + bias4.y) * xr[r2 + 1];
                v      += (acc[mf][2][r2] + bias4.z) * xr[r2 + 2];
                v      += (acc[mf][3][r2] + bias4.w) * xr[r2 + 3];
                int lrow = lrow0 + r2;
                Out[((size_t)bidx * T_DIM + (t0 + lrow)) * D_DIM + dbase + dloc] = silu_f(v);
            }
        }
    }
}

extern "C" void kernel_launch(void* const* d_in, const int* in_sizes, int n_in,
                              void* d_out, int out_size, void* d_ws, size_t ws_size,
                              hipStream_t stream) {
    const float* x    = (const float*)d_in[0];  // [B,T,D]
    const float* w1   = (const float*)d_in[1];  // [H,D]
    const float* w2w  = (const float*)d_in[2];  // [D*W,H]
    const float* w2b  = (const float*)d_in[3];  // [D*W]
    float* out = (float*)d_out;

    // Workspace: ws0 = xb [M,D] bf16 (later reused for w2wb [N2,H] bf16),
    //            ws1 = w1b [H,D] bf16, ws2 = hb [M,H] bf16.
    unsigned short* ws0 = (unsigned short*)d_ws;
    unsigned short* ws1 = ws0 + (size_t)M_DIM * D_DIM;
    unsigned short* ws2 = ws1 + (size_t)H_DIM * D_DIM;

    const int CT = 256;
    {
        int n4 = (M_DIM * D_DIM) / 4;
        cvt_f32_to_bf16<<<(n4 + CT - 1) / CT, CT, 0, stream>>>(x, ws0, n4);
    }
    {
        int n4 = (H_DIM * D_DIM) / 4;
        cvt_f32_to_bf16<<<(n4 + CT - 1) / CT, CT, 0, stream>>>(w1, ws1, n4);
    }
    // GEMM1: hb = silu(xb @ w1b^T)  [8192, 2048]
    gemm8p<0><<<dim3(H_DIM / BN, M_DIM / BM), 512, 0, stream>>>(
        ws0, ws1, M_DIM, H_DIM, D_DIM, ws2, nullptr, nullptr, nullptr);
    // convert w2_w into ws0 (xb now dead)
    {
        int n4 = (N2_DIM * H_DIM) / 4;
        cvt_f32_to_bf16<<<(n4 + CT - 1) / CT, CT, 0, stream>>>(w2w, ws0, n4);
    }
    // GEMM2 + fused bias/conv/silu -> out
    gemm8p<1><<<dim3(N2_DIM / BN, M_DIM / BM), 512, 0, stream>>>(
        ws2, ws0, M_DIM, N2_DIM, H_DIM, nullptr, w2b, x, out);
}